// Round 1
// baseline (737.920 us; speedup 1.0000x reference)
//
#include <hip/hip_runtime.h>
#include <hip/hip_bf16.h>

#define C1_CONST 4.7e-9f
#define NCHUNK_STEPS 512
#define WARM_STEPS 768

// Broadcast lane k's value of v to all lanes (wave-uniform result -> SGPR).
__device__ __forceinline__ float bc(float v, int k) {
    return __int_as_float(__builtin_amdgcn_readlane(__float_as_int(v), k));
}

// Per-lane 32-dot: sum_k w[k] * h[k-th lane's h], with 4 accumulators.
// w[] must be a fully-register-resident per-lane array (constant indices).
__device__ __forceinline__ float dot32(const float* w, float h, float bias) {
    float a0 = bias, a1 = 0.f, a2 = 0.f, a3 = 0.f;
#pragma unroll
    for (int k = 0; k < 32; k += 4) {
        a0 = fmaf(w[k + 0], bc(h, k + 0), a0);
        a1 = fmaf(w[k + 1], bc(h, k + 1), a1);
        a2 = fmaf(w[k + 2], bc(h, k + 2), a2);
        a3 = fmaf(w[k + 3], bc(h, k + 3), a3);
    }
    return (a0 + a1) + (a2 + a3);
}

// Kernel 1: parallel precompute of per-step scalars {P1, P2*v, dp_r, 0}.
// Uses P0 == 1 identity (g0 = g1+g2 exactly), so only these 3 are needed.
__global__ void precompute_kernel(const float* __restrict__ v_in,
                                  const float* __restrict__ vs_r,
                                  const float* __restrict__ fs,
                                  float4* __restrict__ ws4, int T) {
    int t = blockIdx.x * blockDim.x + threadIdx.x;
    if (t >= T) return;
    float f   = fs[t];
    float vr  = vs_r[t];
    float c1r = 1.0f / (2.0f * C1_CONST * f);
    float r0  = c1r * vr / (c1r + vr);
    float g0  = 1.0f / r0;
    float g1  = 1.0f / c1r;
    float g2  = 1.0f / vr;
    float S   = g0 + g1 + g2;
    float P1  = 2.0f * g1 / S;
    float P2  = 2.0f * g2 / S;
    ws4[t] = make_float4(P1, P2 * v_in[t], r0 / 3000.0f, 0.0f);
}

// Kernel 2: chunked sequential scan. One wave (64 threads) per chunk of
// NCHUNK_STEPS outputs, warm-up of WARM_STEPS steps from b1=0 exploiting the
// fading memory of the recurrence. Lane i holds MLP row i in VGPRs.
template <bool INLINE_PRE>
__global__ __launch_bounds__(64) void scan_kernel(
    const float* __restrict__ v_in, const float* __restrict__ vs_r,
    const float* __restrict__ fs,
    const float* __restrict__ W_in, const float* __restrict__ b_in,
    const float* __restrict__ W_h,  const float* __restrict__ b_h,
    const float* __restrict__ W_out, const float* __restrict__ b_out,
    const float4* __restrict__ ws4, float* __restrict__ out, int T) {
    const int lane = threadIdx.x & 63;
    const int i    = lane & 31;  // MLP row (lanes 32-63 duplicate 0-31)

    // ---- load weights into registers (per-lane row i) ----
    float wi0 = W_in[2 * i], wi1 = W_in[2 * i + 1], bi = b_in[i];
    float whA[32], whB[32], wo[32];
#pragma unroll
    for (int k = 0; k < 32; ++k) {
        whA[k] = W_h[i * 32 + k];           // W_h[0][i][k]
        whB[k] = W_h[1024 + i * 32 + k];    // W_h[1][i][k]
        wo[k]  = W_out[k];                  // W_out[0][k] (all lanes need all)
    }
    float bhA = b_h[i], bhB = b_h[32 + i], bo = b_out[0];

    const int ts = blockIdx.x * NCHUNK_STEPS;      // first output step
    if (ts >= T) return;
    const int te = min(T, ts + NCHUNK_STEPS);      // end (exclusive)
    const int t0 = max(0, ts - WARM_STEPS);        // warm-up start (b1=0 there;
                                                   // exact if clamped to 0)
    float b1 = 0.0f;

    auto load_pre = [&](int t, float& P1, float& pv, float& dr) {
        if constexpr (INLINE_PRE) {
            float f   = fs[t];
            float vr  = vs_r[t];
            float c1r = 1.0f / (2.0f * C1_CONST * f);
            float r0  = c1r * vr / (c1r + vr);
            float g0  = 1.0f / r0;
            float g1  = 1.0f / c1r;
            float g2  = 1.0f / vr;
            float S   = g0 + g1 + g2;
            P1 = 2.0f * g1 / S;
            pv = (2.0f * g2 / S) * v_in[t];
            dr = r0 / 3000.0f;
        } else {
            float4 d = ws4[t];   // uniform address -> scalar load
            P1 = d.x; pv = d.y; dr = d.z;
        }
    };

    float P1, pv, dr;
    load_pre(t0, P1, pv, dr);

    for (int t = t0; t < te; ++t) {
        // prefetch next step's scalars (independent of this step's compute)
        int tn = (t + 1 < T) ? (t + 1) : (T - 1);
        float nP1, npv, ndr;
        load_pre(tn, nP1, npv, ndr);

        // dp_a = P1*b1 + P2*v   (P0 == 1 -> a0 term vanishes)
        float dp_a = fmaf(P1, b1, pv);

        // MLP: 2 -> 32 -> 32 -> 32 -> 1
        float h1 = fmaxf(fmaf(wi0, dp_a, fmaf(wi1, dr, bi)), 0.0f);
        float h2 = fmaxf(dot32(whA, h1, bhA), 0.0f);
        float h3 = fmaxf(dot32(whB, h2, bhB), 0.0f);
        float dp_b = dot32(wo, h3, bo);

        float o = 0.5f * (dp_a + dp_b);
        b1 = (dp_a + dp_b) - b1;   // b1' = dp_b + (P1-1)*b1 + P2*v

        if (t >= ts && lane == 0) out[t] = o;

        P1 = nP1; pv = npv; dr = ndr;
    }
}

extern "C" void kernel_launch(void* const* d_in, const int* in_sizes, int n_in,
                              void* d_out, int out_size, void* d_ws, size_t ws_size,
                              hipStream_t stream) {
    const float* v_in  = (const float*)d_in[0];
    const float* vs_r  = (const float*)d_in[1];
    const float* fs    = (const float*)d_in[2];
    const float* W_in  = (const float*)d_in[3];
    const float* b_in  = (const float*)d_in[4];
    const float* W_h   = (const float*)d_in[5];
    const float* b_h   = (const float*)d_in[6];
    const float* W_out = (const float*)d_in[7];
    const float* b_out = (const float*)d_in[8];
    float* out = (float*)d_out;

    const int T = in_sizes[0];
    const int nChunks = (T + NCHUNK_STEPS - 1) / NCHUNK_STEPS;
    const size_t need = (size_t)T * sizeof(float4);

    if (ws_size >= need) {
        float4* ws4 = (float4*)d_ws;
        precompute_kernel<<<(T + 255) / 256, 256, 0, stream>>>(v_in, vs_r, fs, ws4, T);
        scan_kernel<false><<<nChunks, 64, 0, stream>>>(
            v_in, vs_r, fs, W_in, b_in, W_h, b_h, W_out, b_out, ws4, out, T);
    } else {
        scan_kernel<true><<<nChunks, 64, 0, stream>>>(
            v_in, vs_r, fs, W_in, b_in, W_h, b_h, W_out, b_out, nullptr, out, T);
    }
}

// Round 2
// 650.645 us; speedup vs baseline: 1.1341x; 1.1341x over previous
//
#include <hip/hip_runtime.h>
#include <hip/hip_bf16.h>

#define C1_CONST 4.7e-9f
#define CHUNK 256
#define WARM  384

// Broadcast lane K (within each 32-lane group) to all lanes of that group.
// ds_swizzle BitMode: new_lane = ((lane & and) | or) ^ xor ; and=0, or=K, xor=0.
template <int K>
__device__ __forceinline__ float swz(float v) {
    return __int_as_float(__builtin_amdgcn_ds_swizzle(__float_as_int(v), (K) << 5));
}

#define R32(M) M(0) M(1) M(2) M(3) M(4) M(5) M(6) M(7) M(8) M(9) M(10) M(11) \
               M(12) M(13) M(14) M(15) M(16) M(17) M(18) M(19) M(20) M(21) M(22) \
               M(23) M(24) M(25) M(26) M(27) M(28) M(29) M(30) M(31)

#define R32P(M) M(0,s0) M(1,s1) M(2,s2) M(3,s3) M(4,s0) M(5,s1) M(6,s2) M(7,s3) \
                M(8,s0) M(9,s1) M(10,s2) M(11,s3) M(12,s0) M(13,s1) M(14,s2) M(15,s3) \
                M(16,s0) M(17,s1) M(18,s2) M(19,s3) M(20,s0) M(21,s1) M(22,s2) M(23,s3) \
                M(24,s0) M(25,s1) M(26,s2) M(27,s3) M(28,s0) M(29,s1) M(30,s2) M(31,s3)

// Kernel 1: parallel precompute of per-step scalars {P1, P2*v, dp_r, 0}.
// Uses P0 == 1 identity (g0 = g1+g2 exactly).
__global__ void precompute_kernel(const float* __restrict__ v_in,
                                  const float* __restrict__ vs_r,
                                  const float* __restrict__ fs,
                                  float4* __restrict__ ws4, int T) {
    int t = blockIdx.x * blockDim.x + threadIdx.x;
    if (t >= T) return;
    float f   = fs[t];
    float vr  = vs_r[t];
    float c1r = 1.0f / (2.0f * C1_CONST * f);
    float r0  = c1r * vr / (c1r + vr);
    float g1  = 1.0f / c1r;
    float g2  = 1.0f / vr;
    float S   = 2.0f * (g1 + g2);   // g0 = g1+g2
    float P1  = 2.0f * g1 / S;
    float P2  = 2.0f * g2 / S;
    ws4[t] = make_float4(P1, P2 * v_in[t], r0 / 3000.0f, 0.0f);
}

// Kernel 2: chunked sequential scan, TWO chunks per wave (lanes 0-31 = chunk A,
// lanes 32-63 = chunk B). Within-group broadcasts via ds_swizzle. All weights
// live in named scalar registers (macro-expanded; no arrays => guaranteed SROA).
template <bool INLINE_PRE>
__global__ __launch_bounds__(64) void scan_kernel(
    const float* __restrict__ v_in, const float* __restrict__ vs_r,
    const float* __restrict__ fs,
    const float* __restrict__ W_in, const float* __restrict__ b_in,
    const float* __restrict__ W_h,  const float* __restrict__ b_h,
    const float* __restrict__ W_out, const float* __restrict__ b_out,
    const float4* __restrict__ ws4, float* __restrict__ out, int T) {
    const int lane = threadIdx.x & 63;
    const int i    = lane & 31;  // MLP row

    // ---- weights: named per-lane scalar registers ----
#define DECLW(k) float whA_##k = W_h[i * 32 + (k)]; \
                 float whB_##k = W_h[1024 + i * 32 + (k)]; \
                 float wo_##k  = W_out[(k)];
    R32(DECLW)
#undef DECLW
    float wi0 = W_in[2 * i], wi1 = W_in[2 * i + 1], bi = b_in[i];
    float bhA = b_h[i], bhB = b_h[32 + i], bo = b_out[0];

    const int chunkIdx = blockIdx.x * 2 + (lane >> 5);
    const int ts = chunkIdx * CHUNK;         // first output step of this half

    auto clampT = [&](int tt) { return min(max(tt, 0), T - 1); };

    auto load_pre = [&](int tt, float& P1, float& pv, float& dr) {
        int tc = clampT(tt);
        if constexpr (INLINE_PRE) {
            float f   = fs[tc];
            float vr  = vs_r[tc];
            float c1r = 1.0f / (2.0f * C1_CONST * f);
            float r0  = c1r * vr / (c1r + vr);
            float g1  = 1.0f / c1r;
            float g2  = 1.0f / vr;
            float S   = 2.0f * (g1 + g2);
            P1 = 2.0f * g1 / S;
            pv = (2.0f * g2 / S) * v_in[tc];
            dr = r0 / 3000.0f;
        } else {
            float4 d = ws4[tc];
            P1 = d.x; pv = d.y; dr = d.z;
        }
    };

    float b1 = 0.0f;
    int t = ts - WARM;
    float P1, pv, dr;
    load_pre(t, P1, pv, dr);

    for (int j = -WARM; j < CHUNK; ++j, ++t) {
        // prefetch next step's scalars (independent of this step's compute)
        float nP1, npv, ndr;
        load_pre(t + 1, nP1, npv, ndr);

        // dp_a = P1*b1 + P2*v   (P0 == 1 -> a0 term vanishes)
        float dp_a = fmaf(P1, b1, pv);

        // MLP: 2 -> 32 -> 32 -> 32 -> 1, per-32-lane-group broadcasts
        float h1 = fmaxf(fmaf(wi0, dp_a, fmaf(wi1, dr, bi)), 0.0f);

        float s0 = bhA, s1 = 0.f, s2 = 0.f, s3 = 0.f;
#define DA(k, a) a = fmaf(whA_##k, swz<k>(h1), a);
        R32P(DA)
#undef DA
        float h2 = fmaxf((s0 + s1) + (s2 + s3), 0.0f);

        s0 = bhB; s1 = 0.f; s2 = 0.f; s3 = 0.f;
#define DB(k, a) a = fmaf(whB_##k, swz<k>(h2), a);
        R32P(DB)
#undef DB
        float h3 = fmaxf((s0 + s1) + (s2 + s3), 0.0f);

        s0 = bo; s1 = 0.f; s2 = 0.f; s3 = 0.f;
#define DOut(k, a) a = fmaf(wo_##k, swz<k>(h3), a);
        R32P(DOut)
#undef DOut
        float dp_b = (s0 + s1) + (s2 + s3);

        float sum = dp_a + dp_b;
        if (((lane & 31) == 0) && (j >= 0) && (t < T)) out[t] = 0.5f * sum;

        b1 = sum - b1;          // b1' = dp_b + (P1-1)*b1 + P2*v
        if (t < 0) b1 = 0.0f;   // warm-up clamp: exact b1=0 entering t=0

        P1 = nP1; pv = npv; dr = ndr;
    }
}

extern "C" void kernel_launch(void* const* d_in, const int* in_sizes, int n_in,
                              void* d_out, int out_size, void* d_ws, size_t ws_size,
                              hipStream_t stream) {
    const float* v_in  = (const float*)d_in[0];
    const float* vs_r  = (const float*)d_in[1];
    const float* fs    = (const float*)d_in[2];
    const float* W_in  = (const float*)d_in[3];
    const float* b_in  = (const float*)d_in[4];
    const float* W_h   = (const float*)d_in[5];
    const float* b_h   = (const float*)d_in[6];
    const float* W_out = (const float*)d_in[7];
    const float* b_out = (const float*)d_in[8];
    float* out = (float*)d_out;

    const int T = in_sizes[0];
    const int nChunks = (T + CHUNK - 1) / CHUNK;
    const int nWaves  = (nChunks + 1) / 2;
    const size_t need = (size_t)T * sizeof(float4);

    if (ws_size >= need) {
        float4* ws4 = (float4*)d_ws;
        precompute_kernel<<<(T + 255) / 256, 256, 0, stream>>>(v_in, vs_r, fs, ws4, T);
        scan_kernel<false><<<nWaves, 64, 0, stream>>>(
            v_in, vs_r, fs, W_in, b_in, W_h, b_h, W_out, b_out, ws4, out, T);
    } else {
        scan_kernel<true><<<nWaves, 64, 0, stream>>>(
            v_in, vs_r, fs, W_in, b_in, W_h, b_h, W_out, b_out, nullptr, out, T);
    }
}

// Round 3
// 388.302 us; speedup vs baseline: 1.9004x; 1.6756x over previous
//
#include <hip/hip_runtime.h>
#include <hip/hip_bf16.h>

#define C1_CONST 4.7e-9f
#define CHUNK 240
#define WARM  192

// Wave-uniform broadcast of lane k (k in 0..31; halves hold identical data).
__device__ __forceinline__ float bc(float v, int k) {
    return __int_as_float(__builtin_amdgcn_readlane(__float_as_int(v), k));
}

// ds_swizzle BitMode xor butterfly within each 32-lane group.
template <int OFF>
__device__ __forceinline__ float swz(float v) {
    return __int_as_float(__builtin_amdgcn_ds_swizzle(__float_as_int(v), OFF));
}

#define R32(M) M(0) M(1) M(2) M(3) M(4) M(5) M(6) M(7) M(8) M(9) M(10) M(11) \
               M(12) M(13) M(14) M(15) M(16) M(17) M(18) M(19) M(20) M(21) M(22) \
               M(23) M(24) M(25) M(26) M(27) M(28) M(29) M(30) M(31)

#define R32P(M) M(0,s0) M(1,s1) M(2,s2) M(3,s3) M(4,s0) M(5,s1) M(6,s2) M(7,s3) \
                M(8,s0) M(9,s1) M(10,s2) M(11,s3) M(12,s0) M(13,s1) M(14,s2) M(15,s3) \
                M(16,s0) M(17,s1) M(18,s2) M(19,s3) M(20,s0) M(21,s1) M(22,s2) M(23,s3) \
                M(24,s0) M(25,s1) M(26,s2) M(27,s3) M(28,s0) M(29,s1) M(30,s2) M(31,s3)

// Kernel 1: parallel precompute of per-step scalars {P1, P2*v, dp_r, 0}.
// Uses the P0 == 1 identity (g0 = g1+g2 exactly).
__global__ void precompute_kernel(const float* __restrict__ v_in,
                                  const float* __restrict__ vs_r,
                                  const float* __restrict__ fs,
                                  float4* __restrict__ ws4, int T) {
    int t = blockIdx.x * blockDim.x + threadIdx.x;
    if (t >= T) return;
    float f   = fs[t];
    float vr  = vs_r[t];
    float c1r = 1.0f / (2.0f * C1_CONST * f);
    float r0  = c1r * vr / (c1r + vr);
    float g1  = 1.0f / c1r;
    float g2  = 1.0f / vr;
    float S   = 2.0f * (g1 + g2);   // g0 = g1+g2
    float P1  = 2.0f * g1 / S;
    float P2  = 2.0f * g2 / S;
    ws4[t] = make_float4(P1, P2 * v_in[t], r0 / 3000.0f, 0.0f);
}

// Kernel 2: ONE chunk per wave. t is wave-uniform -> ws4 loads are s_load,
// h-broadcasts are v_readlane (VALU pipe, scales with occupancy; no LDS-pipe
// contention). Rows duplicated across the two 32-lane halves. Weights in
// named registers; __launch_bounds__(64,2) gives the allocator a 256-VGPR
// budget so they stay arch-VGPR-resident.
template <bool INLINE_PRE>
__global__ __launch_bounds__(64, 2) void scan_kernel(
    const float* __restrict__ v_in, const float* __restrict__ vs_r,
    const float* __restrict__ fs,
    const float* __restrict__ W_in, const float* __restrict__ b_in,
    const float* __restrict__ W_h,  const float* __restrict__ b_h,
    const float* __restrict__ W_out, const float* __restrict__ b_out,
    const float4* __restrict__ ws4, float* __restrict__ out, int T) {
    const int lane = threadIdx.x & 63;
    const int i    = lane & 31;  // MLP row (halves duplicate)

    // ---- weights: named per-lane registers ----
#define DECLW(k) float whA_##k = W_h[i * 32 + (k)]; \
                 float whB_##k = W_h[1024 + i * 32 + (k)];
    R32(DECLW)
#undef DECLW
    float wi0 = W_in[2 * i], wi1 = W_in[2 * i + 1], bi = b_in[i];
    float bhA = b_h[i], bhB = b_h[32 + i], bo = b_out[0];
    float woi = W_out[i];

    const int ts = blockIdx.x * CHUNK;       // first output step of this chunk
    if (ts >= T) return;

    auto clampT = [&](int tt) { return min(max(tt, 0), T - 1); };

    auto load_pre = [&](int tt, float& P1, float& pv, float& dr) {
        int tc = clampT(tt);
        if constexpr (INLINE_PRE) {
            float f   = fs[tc];
            float vr  = vs_r[tc];
            float c1r = 1.0f / (2.0f * C1_CONST * f);
            float r0  = c1r * vr / (c1r + vr);
            float g1  = 1.0f / c1r;
            float g2  = 1.0f / vr;
            float S   = 2.0f * (g1 + g2);
            P1 = 2.0f * g1 / S;
            pv = (2.0f * g2 / S) * v_in[tc];
            dr = r0 / 3000.0f;
        } else {
            float4 d = ws4[tc];   // wave-uniform address -> s_load_dwordx4
            P1 = d.x; pv = d.y; dr = d.z;
        }
    };

    float b1 = 0.0f;             // wave-uniform carry (replicated per lane)
    int t = ts - WARM;
    float P1, pv, dr;
    load_pre(t, P1, pv, dr);

    for (int j = -WARM; j < CHUNK; ++j, ++t) {
        // prefetch next step's scalars (independent of this step's compute)
        float nP1, npv, ndr;
        load_pre(t + 1, nP1, npv, ndr);

        // dp_a = P1*b1 + P2*v   (P0 == 1 -> a0 term vanishes)
        float dp_a = fmaf(P1, b1, pv);

        // input layer: 2 -> 32, per-lane row i
        float h1 = fmaxf(fmaf(wi0, dp_a, fmaf(wi1, dr, bi)), 0.0f);

        // hidden layer A: 32 -> 32 (readlane broadcasts, VALU only)
        float h2;
        {
#define BCA(k) const float u##k = bc(h1, k);
            R32(BCA)
#undef BCA
            float s0 = bhA, s1 = 0.f, s2 = 0.f, s3 = 0.f;
#define FA(k, a) a = fmaf(u##k, whA_##k, a);
            R32P(FA)
#undef FA
            h2 = fmaxf((s0 + s1) + (s2 + s3), 0.0f);
        }

        // hidden layer B: 32 -> 32
        float h3;
        {
#define BCB(k) const float u##k = bc(h2, k);
            R32(BCB)
#undef BCB
            float s0 = bhB, s1 = 0.f, s2 = 0.f, s3 = 0.f;
#define FB(k, a) a = fmaf(u##k, whB_##k, a);
            R32P(FB)
#undef FB
            h3 = fmaxf((s0 + s1) + (s2 + s3), 0.0f);
        }

        // output layer: 32 -> 1 via xor butterfly within each 32-lane group
        float p = woi * h3;
        p += swz<0x041F>(p);   // xor 1
        p += swz<0x081F>(p);   // xor 2
        p += swz<0x101F>(p);   // xor 4
        p += swz<0x201F>(p);   // xor 8
        p += swz<0x401F>(p);   // xor 16
        float dp_b = p + bo;

        float sum = dp_a + dp_b;
        if (lane == 0 && j >= 0 && t < T) out[t] = 0.5f * sum;

        b1 = sum - b1;          // b1' = dp_b + (P1-1)*b1 + P2*v
        if (t < 0) b1 = 0.0f;   // warm-up clamp: exact b1=0 entering t=0

        P1 = nP1; pv = npv; dr = ndr;
    }
}

extern "C" void kernel_launch(void* const* d_in, const int* in_sizes, int n_in,
                              void* d_out, int out_size, void* d_ws, size_t ws_size,
                              hipStream_t stream) {
    const float* v_in  = (const float*)d_in[0];
    const float* vs_r  = (const float*)d_in[1];
    const float* fs    = (const float*)d_in[2];
    const float* W_in  = (const float*)d_in[3];
    const float* b_in  = (const float*)d_in[4];
    const float* W_h   = (const float*)d_in[5];
    const float* b_h   = (const float*)d_in[6];
    const float* W_out = (const float*)d_in[7];
    const float* b_out = (const float*)d_in[8];
    float* out = (float*)d_out;

    const int T = in_sizes[0];
    const int nChunks = (T + CHUNK - 1) / CHUNK;   // one wave per chunk
    const size_t need = (size_t)T * sizeof(float4);

    if (ws_size >= need) {
        float4* ws4 = (float4*)d_ws;
        precompute_kernel<<<(T + 255) / 256, 256, 0, stream>>>(v_in, vs_r, fs, ws4, T);
        scan_kernel<false><<<nChunks, 64, 0, stream>>>(
            v_in, vs_r, fs, W_in, b_in, W_h, b_h, W_out, b_out, ws4, out, T);
    } else {
        scan_kernel<true><<<nChunks, 64, 0, stream>>>(
            v_in, vs_r, fs, W_in, b_in, W_h, b_h, W_out, b_out, nullptr, out, T);
    }
}

// Round 5
// 290.323 us; speedup vs baseline: 2.5417x; 1.3375x over previous
//
#include <hip/hip_runtime.h>
#include <hip/hip_bf16.h>

#define C1_CONST 4.7e-9f
#define CHUNK 15      // output steps per chunk
#define WARM  192     // warm-up steps (b1 fading-memory)
#define CPW   32      // chunks per wave (MFMA batch)

typedef _Float16 f16;
typedef f16   f16x2  __attribute__((ext_vector_type(2)));
typedef f16   f16x8  __attribute__((ext_vector_type(8)));
typedef float f32x16 __attribute__((ext_vector_type(16)));

#define MFMA(A, B, C) __builtin_amdgcn_mfma_f32_32x32x16_f16((A), (B), (C), 0, 0, 0)

// Dekker split: x = hi + lo/1024, hi/lo f16. Scaling by 1024 keeps lo in the
// f16 normal range (weight/activation residuals ~2^-11*x would otherwise be
// denormal and risk being flushed by the matrix pipe).
__device__ __forceinline__ void split2(float x0, float x1, f16x2& hi, f16x2& lo) {
    hi = __builtin_bit_cast(f16x2, __builtin_amdgcn_cvt_pkrtz(x0, x1));
    float r0 = (x0 - (float)hi[0]) * 1024.0f;
    float r1 = (x1 - (float)hi[1]) * 1024.0f;
    lo = __builtin_bit_cast(f16x2, __builtin_amdgcn_cvt_pkrtz(r0, r1));
}

// Kernel 1: parallel precompute of per-step scalars {P1, P2*v, dp_r, 0}.
// Uses the P0 == 1 identity (g0 = g1+g2 exactly).
__global__ void precompute_kernel(const float* __restrict__ v_in,
                                  const float* __restrict__ vs_r,
                                  const float* __restrict__ fs,
                                  float4* __restrict__ ws4, int T) {
    int t = blockIdx.x * blockDim.x + threadIdx.x;
    if (t >= T) return;
    float f   = fs[t];
    float vr  = vs_r[t];
    float c1r = 1.0f / (2.0f * C1_CONST * f);
    float r0  = c1r * vr / (c1r + vr);
    float g1  = 1.0f / c1r;
    float g2  = 1.0f / vr;
    float S   = 2.0f * (g1 + g2);   // g0 = g1+g2
    float P1  = 2.0f * g1 / S;
    float P2  = 2.0f * g2 / S;
    ws4[t] = make_float4(P1, P2 * v_in[t], r0 / 3000.0f, 0.0f);
}

// Kernel 2: 32 chunks per wave, hidden layers via v_mfma_f32_32x32x16_f16.
// chunk = MFMA column n = lane&31; half h = lane>>5.
// A operand (weights, M=outfeat x K=infeat): m=lane&31, k = 16*s + 8*h + jj.
// B operand (activations, K x N=chunk):      n=lane&31, k = 16*s + 8*h + jj.
// (Any common k-slot permutation cancels between A and B.)
// C/D (verified): col=lane&31, row=(reg&3)+8*(reg>>2)+4*h.
template <bool INLINE_PRE>
__global__ __launch_bounds__(64, 1) void scan_kernel(
    const float* __restrict__ v_in, const float* __restrict__ vs_r,
    const float* __restrict__ fs,
    const float* __restrict__ W_in, const float* __restrict__ b_in,
    const float* __restrict__ W_h,  const float* __restrict__ b_h,
    const float* __restrict__ W_out, const float* __restrict__ b_out,
    const float4* __restrict__ ws4, float* __restrict__ out, int T) {
    const int lane = threadIdx.x & 63;
    const int c    = lane & 31;   // chunk slot / MFMA col / weight row m
    const int h    = lane >> 5;
    const int xaddr = (lane ^ 32) << 2;   // ds_bpermute addr for xor-32

    auto xr32 = [&](float v) {
        return __int_as_float(__builtin_amdgcn_ds_bpermute(xaddr, __float_as_int(v)));
    };

    // ---- MFMA A fragments for the two hidden layers (hi + lo*1024) ----
    f16x8 AhA0, AlA0, AhA1, AlA1, AhB0, AlB0, AhB1, AlB1;
#pragma unroll
    for (int jj = 0; jj < 8; ++jj) {
        int k0 = 8 * h + jj, k1 = 16 + 8 * h + jj;
        float wa0 = W_h[c * 32 + k0], wa1 = W_h[c * 32 + k1];
        float wb0 = W_h[1024 + c * 32 + k0], wb1 = W_h[1024 + c * 32 + k1];
        f16 t;
        t = (f16)wa0; AhA0[jj] = t; AlA0[jj] = (f16)((wa0 - (float)t) * 1024.0f);
        t = (f16)wa1; AhA1[jj] = t; AlA1[jj] = (f16)((wa1 - (float)t) * 1024.0f);
        t = (f16)wb0; AhB0[jj] = t; AlB0[jj] = (f16)((wb0 - (float)t) * 1024.0f);
        t = (f16)wb1; AhB1[jj] = t; AlB1[jj] = (f16)((wb1 - (float)t) * 1024.0f);
    }

    // ---- biases in C/D layout; W_out by C/D row; zero C frag ----
    f32x16 bAf, bBf, zf;
    float wo_r[16];
#pragma unroll
    for (int r = 0; r < 16; ++r) {
        int row = (r & 3) + 8 * (r >> 2) + 4 * h;
        bAf[r] = b_h[row];
        bBf[r] = b_h[32 + row];
        wo_r[r] = W_out[row];
        zf[r] = 0.0f;
    }
    const float bo = b_out[0];

    // ---- input-layer constants for this lane's B slots ----
    float wi0c[16], wi1c[16], bic[16];   // slot s*8+jj -> k = 16*s + 8*h + jj
#pragma unroll
    for (int s = 0; s < 2; ++s)
#pragma unroll
        for (int jj = 0; jj < 8; ++jj) {
            int k = 16 * s + 8 * h + jj;
            wi0c[s * 8 + jj] = W_in[2 * k];
            wi1c[s * 8 + jj] = W_in[2 * k + 1];
            bic[s * 8 + jj]  = b_in[k];
        }

    const int cg = blockIdx.x * CPW + c;   // global chunk id
    const int ts = cg * CHUNK;             // first output step of this chunk

    auto load_pre = [&](int tt, float& P1, float& pv, float& dr) {
        int tc = min(max(tt, 0), T - 1);
        if constexpr (INLINE_PRE) {
            float f   = fs[tc];
            float vr  = vs_r[tc];
            float c1r = 1.0f / (2.0f * C1_CONST * f);
            float r0  = c1r * vr / (c1r + vr);
            float g1  = 1.0f / c1r;
            float g2  = 1.0f / vr;
            float S   = 2.0f * (g1 + g2);
            P1 = 2.0f * g1 / S;
            pv = (2.0f * g2 / S) * v_in[tc];
            dr = r0 / 3000.0f;
        } else {
            float4 d = ws4[tc];
            P1 = d.x; pv = d.y; dr = d.z;
        }
    };

    float b1 = 0.0f;
    float P1, pv, dr;
    load_pre(ts - WARM, P1, pv, dr);

    for (int j = -WARM; j < CHUNK; ++j) {
        const int t = ts + j;
        // prefetch next step's scalars (independent of this step's compute)
        float nP1, npv, ndr;
        load_pre(t + 1, nP1, npv, ndr);

        // dp_a = P1*b1 + P2*v   (P0 == 1 -> a0 term vanishes)
        const float dp_a = fmaf(P1, b1, pv);

        // ---- input layer 2->32, directly in B layout ----
        float hv[16];
#pragma unroll
        for (int u = 0; u < 16; ++u)
            hv[u] = fmaxf(fmaf(wi0c[u], dp_a, fmaf(wi1c[u], dr, bic[u])), 0.0f);
        f16x8 B0h, B0l, B1h, B1l;
#pragma unroll
        for (int q = 0; q < 4; ++q) {
            f16x2 hi2, lo2;
            split2(hv[2 * q], hv[2 * q + 1], hi2, lo2);
            B0h[2 * q] = hi2[0]; B0h[2 * q + 1] = hi2[1];
            B0l[2 * q] = lo2[0]; B0l[2 * q + 1] = lo2[1];
            split2(hv[8 + 2 * q], hv[8 + 2 * q + 1], hi2, lo2);
            B1h[2 * q] = hi2[0]; B1h[2 * q + 1] = hi2[1];
            B1l[2 * q] = lo2[0]; B1l[2 * q + 1] = lo2[1];
        }

        // ---- hidden layer A ----
        f32x16 acc = MFMA(AhA0, B0h, bAf);
        acc = MFMA(AhA1, B1h, acc);
        f32x16 acc2 = MFMA(AhA0, B0l, zf);
        acc2 = MFMA(AlA0, B0h, acc2);
        acc2 = MFMA(AhA1, B1l, acc2);
        acc2 = MFMA(AlA1, B1h, acc2);
        float v[16];
#pragma unroll
        for (int r = 0; r < 16; ++r)
            v[r] = fmaxf(fmaf(acc2[r], 1.0f / 1024.0f, acc[r]), 0.0f);

        // ---- C/D -> B exchange (cross-half rows via ds_bpermute xor 32) ----
        float recv[8];
#pragma unroll
        for (int q = 0; q < 8; ++q) {
            int i0 = (q < 4) ? q + 4 : q + 8;   // what h=0 sends (rows 8-11,24-27)
            int i1 = (q < 4) ? q     : q + 4;   // what h=1 sends (rows 4-7,20-23)
            recv[q] = xr32(h ? v[i1] : v[i0]);
        }
        float w2[16];
#pragma unroll
        for (int jj = 0; jj < 4; ++jj) {
            w2[jj]          = h ? recv[jj]     : v[jj];        // k=8h+jj
            w2[4 + jj]      = h ? v[4 + jj]    : recv[jj];     // k=8h+4+jj
            w2[8 + jj]      = h ? recv[4 + jj] : v[8 + jj];    // k=16+8h+jj
            w2[12 + jj]     = h ? v[12 + jj]   : recv[4 + jj]; // k=16+8h+4+jj
        }
#pragma unroll
        for (int q = 0; q < 4; ++q) {
            f16x2 hi2, lo2;
            split2(w2[2 * q], w2[2 * q + 1], hi2, lo2);
            B0h[2 * q] = hi2[0]; B0h[2 * q + 1] = hi2[1];
            B0l[2 * q] = lo2[0]; B0l[2 * q + 1] = lo2[1];
            split2(w2[8 + 2 * q], w2[8 + 2 * q + 1], hi2, lo2);
            B1h[2 * q] = hi2[0]; B1h[2 * q + 1] = hi2[1];
            B1l[2 * q] = lo2[0]; B1l[2 * q + 1] = lo2[1];
        }

        // ---- hidden layer B ----
        acc = MFMA(AhB0, B0h, bBf);
        acc = MFMA(AhB1, B1h, acc);
        acc2 = MFMA(AhB0, B0l, zf);
        acc2 = MFMA(AlB0, B0h, acc2);
        acc2 = MFMA(AhB1, B1l, acc2);
        acc2 = MFMA(AlB1, B1h, acc2);

        // ---- output layer 32->1: per-lane partial dot over C/D rows ----
        float p0 = 0.f, p1 = 0.f, p2 = 0.f, p3 = 0.f;
#pragma unroll
        for (int r = 0; r < 16; r += 4) {
            p0 = fmaf(wo_r[r],     fmaxf(fmaf(acc2[r],     1.0f / 1024.0f, acc[r]),     0.0f), p0);
            p1 = fmaf(wo_r[r + 1], fmaxf(fmaf(acc2[r + 1], 1.0f / 1024.0f, acc[r + 1]), 0.0f), p1);
            p2 = fmaf(wo_r[r + 2], fmaxf(fmaf(acc2[r + 2], 1.0f / 1024.0f, acc[r + 2]), 0.0f), p2);
            p3 = fmaf(wo_r[r + 3], fmaxf(fmaf(acc2[r + 3], 1.0f / 1024.0f, acc[r + 3]), 0.0f), p3);
        }
        float pd = (p0 + p1) + (p2 + p3);
        const float dp_b = pd + xr32(pd) + bo;   // symmetric: halves stay bit-identical

        const float sum = dp_a + dp_b;
        if (j >= 0) {                 // wave-uniform branch
            if (lane < 32 && t < T) out[t] = 0.5f * sum;
        }
        b1 = sum - b1;                // b1' = dp_b + (P1-1)*b1 + P2*v
        if (t < 0) b1 = 0.0f;         // warm-up clamp: exact b1=0 entering t=0

        P1 = nP1; pv = npv; dr = ndr;
    }
}

extern "C" void kernel_launch(void* const* d_in, const int* in_sizes, int n_in,
                              void* d_out, int out_size, void* d_ws, size_t ws_size,
                              hipStream_t stream) {
    const float* v_in  = (const float*)d_in[0];
    const float* vs_r  = (const float*)d_in[1];
    const float* fs    = (const float*)d_in[2];
    const float* W_in  = (const float*)d_in[3];
    const float* b_in  = (const float*)d_in[4];
    const float* W_h   = (const float*)d_in[5];
    const float* b_h   = (const float*)d_in[6];
    const float* W_out = (const float*)d_in[7];
    const float* b_out = (const float*)d_in[8];
    float* out = (float*)d_out;

    const int T = in_sizes[0];
    const int nChunks = (T + CHUNK - 1) / CHUNK;
    const int nWaves  = (nChunks + CPW - 1) / CPW;
    const size_t need = (size_t)T * sizeof(float4);

    if (ws_size >= need) {
        float4* ws4 = (float4*)d_ws;
        precompute_kernel<<<(T + 255) / 256, 256, 0, stream>>>(v_in, vs_r, fs, ws4, T);
        scan_kernel<false><<<nWaves, 64, 0, stream>>>(
            v_in, vs_r, fs, W_in, b_in, W_h, b_h, W_out, b_out, ws4, out, T);
    } else {
        scan_kernel<true><<<nWaves, 64, 0, stream>>>(
            v_in, vs_r, fs, W_in, b_in, W_h, b_h, W_out, b_out, nullptr, out, T);
    }
}

// Round 6
// 243.184 us; speedup vs baseline: 3.0344x; 1.1938x over previous
//
#include <hip/hip_runtime.h>
#include <hip/hip_bf16.h>

#define C1_CONST 4.7e-9f
#define CHUNK 15      // output steps per chunk
#define WARM  192     // warm-up steps (b1 fading-memory)
#define CPW   32      // chunks per wave (MFMA batch)

typedef _Float16 f16;
typedef unsigned int u32;
typedef f16   f16x8  __attribute__((ext_vector_type(8)));
typedef u32   u32x4  __attribute__((ext_vector_type(4)));
typedef float f32x16 __attribute__((ext_vector_type(16)));

#define MFMA(A, B, C) __builtin_amdgcn_mfma_f32_32x32x16_f16((A), (B), (C), 0, 0, 0)

// Dekker split of a pair: x = hi + lo/1024 (hi,lo f16, packed as u32).
// Scaling by 1024 keeps lo in f16-normal range (residual ~2^-11*x would
// otherwise be denormal and risk flushing in the matrix pipe).
__device__ __forceinline__ void splitp(float x0, float x1, u32& uh, u32& ul) {
    auto hv = __builtin_amdgcn_cvt_pkrtz(x0, x1);
    float h0 = (float)hv[0], h1 = (float)hv[1];
    auto lv = __builtin_amdgcn_cvt_pkrtz((x0 - h0) * 1024.0f, (x1 - h1) * 1024.0f);
    uh = __builtin_bit_cast(u32, hv);
    ul = __builtin_bit_cast(u32, lv);
}

// Kernel 1: parallel precompute of per-step scalars {P1, P2*v, dp_r, 0}.
// Uses the P0 == 1 identity (g0 = g1+g2 exactly).
__global__ void precompute_kernel(const float* __restrict__ v_in,
                                  const float* __restrict__ vs_r,
                                  const float* __restrict__ fs,
                                  float4* __restrict__ ws4, int T) {
    int t = blockIdx.x * blockDim.x + threadIdx.x;
    if (t >= T) return;
    float f   = fs[t];
    float vr  = vs_r[t];
    float c1r = 1.0f / (2.0f * C1_CONST * f);
    float r0  = c1r * vr / (c1r + vr);
    float g1  = 1.0f / c1r;
    float g2  = 1.0f / vr;
    float S   = 2.0f * (g1 + g2);   // g0 = g1+g2
    float P1  = 2.0f * g1 / S;
    float P2  = 2.0f * g2 / S;
    ws4[t] = make_float4(P1, P2 * v_in[t], r0 / 3000.0f, 0.0f);
}

// Kernel 2: 32 chunks per wave, hidden layers via v_mfma_f32_32x32x16_f16.
// chunk = MFMA column n = lane&31; half h = lane>>5.
//
// LOGICAL-K REMAP (exact): MFMA is invariant under any common permutation of
// A/B k-slots. We choose slot (s = which MFMA, h, jj = vector elem) ->
//   k = (jj&3) + 4*h + 8*(jj>>2) + 16*s
// so that half h's B k-set equals exactly the C/D rows it owns
// (row = (reg&3)+8*(reg>>2)+4*h). Consequence: D reg r = jj + 8*s, i.e.
//   B0 slots = relu(D[0..7]), B1 slots = relu(D[8..15])
// with ZERO cross-lane exchange between layers. A fragments and input-layer
// constants use the same permuted k at setup (free).
template <bool INLINE_PRE>
__global__ __launch_bounds__(64, 1) void scan_kernel(
    const float* __restrict__ v_in, const float* __restrict__ vs_r,
    const float* __restrict__ fs,
    const float* __restrict__ W_in, const float* __restrict__ b_in,
    const float* __restrict__ W_h,  const float* __restrict__ b_h,
    const float* __restrict__ W_out, const float* __restrict__ b_out,
    const float4* __restrict__ ws4, float* __restrict__ out, int T) {
    const int lane = threadIdx.x & 63;
    const int c    = lane & 31;   // chunk slot / MFMA col / weight row m
    const int h    = lane >> 5;
    const int xaddr = (lane ^ 32) << 2;   // ds_bpermute addr for xor-32

    auto xr32 = [&](float v) {
        return __int_as_float(__builtin_amdgcn_ds_bpermute(xaddr, __float_as_int(v)));
    };

    // ---- MFMA A fragments for the two hidden layers (hi + lo*1024) ----
    f16x8 AhA0, AlA0, AhA1, AlA1, AhB0, AlB0, AhB1, AlB1;
#pragma unroll
    for (int jj = 0; jj < 8; ++jj) {
        int k0 = (jj & 3) + 4 * h + 8 * (jj >> 2);   // s=0
        int k1 = k0 + 16;                            // s=1
        float wa0 = W_h[c * 32 + k0], wa1 = W_h[c * 32 + k1];
        float wb0 = W_h[1024 + c * 32 + k0], wb1 = W_h[1024 + c * 32 + k1];
        f16 t;
        t = (f16)wa0; AhA0[jj] = t; AlA0[jj] = (f16)((wa0 - (float)t) * 1024.0f);
        t = (f16)wa1; AhA1[jj] = t; AlA1[jj] = (f16)((wa1 - (float)t) * 1024.0f);
        t = (f16)wb0; AhB0[jj] = t; AlB0[jj] = (f16)((wb0 - (float)t) * 1024.0f);
        t = (f16)wb1; AhB1[jj] = t; AlB1[jj] = (f16)((wb1 - (float)t) * 1024.0f);
    }

    // ---- biases in C/D layout; W_out by C/D row; zero C frag ----
    f32x16 bAf, bBf, zf;
    float wo_r[16];
#pragma unroll
    for (int r = 0; r < 16; ++r) {
        int row = (r & 3) + 8 * (r >> 2) + 4 * h;
        bAf[r] = b_h[row];
        bBf[r] = b_h[32 + row];
        wo_r[r] = W_out[row];
        zf[r] = 0.0f;
    }
    const float bo = b_out[0];

    // ---- input-layer constants, in B-slot order u = s*8 + jj ----
    float wi0c[16], wi1c[16], bic[16];
#pragma unroll
    for (int s = 0; s < 2; ++s)
#pragma unroll
        for (int jj = 0; jj < 8; ++jj) {
            int k = (jj & 3) + 4 * h + 8 * (jj >> 2) + 16 * s;
            wi0c[s * 8 + jj] = W_in[2 * k];
            wi1c[s * 8 + jj] = W_in[2 * k + 1];
            bic[s * 8 + jj]  = b_in[k];
        }

    const int cg = blockIdx.x * CPW + c;   // global chunk id
    const int ts = cg * CHUNK;             // first output step of this chunk

    auto load_pre = [&](int tt, float& P1, float& pv, float& dr) {
        int tc = min(max(tt, 0), T - 1);
        if constexpr (INLINE_PRE) {
            float f   = fs[tc];
            float vr  = vs_r[tc];
            float c1r = 1.0f / (2.0f * C1_CONST * f);
            float r0  = c1r * vr / (c1r + vr);
            float g1  = 1.0f / c1r;
            float g2  = 1.0f / vr;
            float S   = 2.0f * (g1 + g2);
            P1 = 2.0f * g1 / S;
            pv = (2.0f * g2 / S) * v_in[tc];
            dr = r0 / 3000.0f;
        } else {
            float4 d = ws4[tc];
            P1 = d.x; pv = d.y; dr = d.z;
        }
    };

    float b1 = 0.0f;
    float P1, pv, dr;
    load_pre(ts - WARM, P1, pv, dr);

    for (int j = -WARM; j < CHUNK; ++j) {
        const int t = ts + j;
        // prefetch next step's scalars (independent of this step's compute)
        float nP1, npv, ndr;
        load_pre(t + 1, nP1, npv, ndr);

        // dp_a = P1*b1 + P2*v   (P0 == 1 -> a0 term vanishes)
        const float dp_a = fmaf(P1, b1, pv);

        // ---- input layer 2->32, directly in B-slot order ----
        float hv[16];
#pragma unroll
        for (int u = 0; u < 16; ++u)
            hv[u] = fmaxf(fmaf(wi0c[u], dp_a, fmaf(wi1c[u], dr, bic[u])), 0.0f);

        u32 ph0, ph1, ph2, ph3, pl0, pl1, pl2, pl3;
        splitp(hv[0], hv[1], ph0, pl0);
        splitp(hv[2], hv[3], ph1, pl1);
        splitp(hv[4], hv[5], ph2, pl2);
        splitp(hv[6], hv[7], ph3, pl3);
        f16x8 B0h = __builtin_bit_cast(f16x8, (u32x4){ph0, ph1, ph2, ph3});
        f16x8 B0l = __builtin_bit_cast(f16x8, (u32x4){pl0, pl1, pl2, pl3});
        splitp(hv[8],  hv[9],  ph0, pl0);
        splitp(hv[10], hv[11], ph1, pl1);
        splitp(hv[12], hv[13], ph2, pl2);
        splitp(hv[14], hv[15], ph3, pl3);
        f16x8 B1h = __builtin_bit_cast(f16x8, (u32x4){ph0, ph1, ph2, ph3});
        f16x8 B1l = __builtin_bit_cast(f16x8, (u32x4){pl0, pl1, pl2, pl3});

        // ---- hidden layer A ----
        f32x16 acc = MFMA(AhA0, B0h, bAf);
        acc = MFMA(AhA1, B1h, acc);
        f32x16 acc2 = MFMA(AhA0, B0l, zf);
        acc2 = MFMA(AlA0, B0h, acc2);
        acc2 = MFMA(AhA1, B1l, acc2);
        acc2 = MFMA(AlA1, B1h, acc2);

        // relu(D) IS the next B (k-remap): B0 <- regs 0..7, B1 <- regs 8..15
        float v[16];
#pragma unroll
        for (int r = 0; r < 16; ++r)
            v[r] = fmaxf(fmaf(acc2[r], 1.0f / 1024.0f, acc[r]), 0.0f);

        splitp(v[0], v[1], ph0, pl0);
        splitp(v[2], v[3], ph1, pl1);
        splitp(v[4], v[5], ph2, pl2);
        splitp(v[6], v[7], ph3, pl3);
        B0h = __builtin_bit_cast(f16x8, (u32x4){ph0, ph1, ph2, ph3});
        B0l = __builtin_bit_cast(f16x8, (u32x4){pl0, pl1, pl2, pl3});
        splitp(v[8],  v[9],  ph0, pl0);
        splitp(v[10], v[11], ph1, pl1);
        splitp(v[12], v[13], ph2, pl2);
        splitp(v[14], v[15], ph3, pl3);
        B1h = __builtin_bit_cast(f16x8, (u32x4){ph0, ph1, ph2, ph3});
        B1l = __builtin_bit_cast(f16x8, (u32x4){pl0, pl1, pl2, pl3});

        // ---- hidden layer B ----
        acc = MFMA(AhB0, B0h, bBf);
        acc = MFMA(AhB1, B1h, acc);
        acc2 = MFMA(AhB0, B0l, zf);
        acc2 = MFMA(AlB0, B0h, acc2);
        acc2 = MFMA(AhB1, B1l, acc2);
        acc2 = MFMA(AlB1, B1h, acc2);

        // ---- output layer 32->1: per-lane partial dot over C/D rows ----
        float p0 = 0.f, p1 = 0.f, p2 = 0.f, p3 = 0.f;
#pragma unroll
        for (int r = 0; r < 16; r += 4) {
            p0 = fmaf(wo_r[r],     fmaxf(fmaf(acc2[r],     1.0f / 1024.0f, acc[r]),     0.0f), p0);
            p1 = fmaf(wo_r[r + 1], fmaxf(fmaf(acc2[r + 1], 1.0f / 1024.0f, acc[r + 1]), 0.0f), p1);
            p2 = fmaf(wo_r[r + 2], fmaxf(fmaf(acc2[r + 2], 1.0f / 1024.0f, acc[r + 2]), 0.0f), p2);
            p3 = fmaf(wo_r[r + 3], fmaxf(fmaf(acc2[r + 3], 1.0f / 1024.0f, acc[r + 3]), 0.0f), p3);
        }
        float pd = (p0 + p1) + (p2 + p3);
        const float dp_b = pd + xr32(pd) + bo;   // symmetric: halves stay bit-identical

        const float sum = dp_a + dp_b;
        if (j >= 0) {                 // wave-uniform branch
            if (lane < 32 && t < T) out[t] = 0.5f * sum;
        }
        b1 = sum - b1;                // b1' = dp_b + (P1-1)*b1 + P2*v
        if (t < 0) b1 = 0.0f;         // warm-up clamp: exact b1=0 entering t=0

        P1 = nP1; pv = npv; dr = ndr;
    }
}

extern "C" void kernel_launch(void* const* d_in, const int* in_sizes, int n_in,
                              void* d_out, int out_size, void* d_ws, size_t ws_size,
                              hipStream_t stream) {
    const float* v_in  = (const float*)d_in[0];
    const float* vs_r  = (const float*)d_in[1];
    const float* fs    = (const float*)d_in[2];
    const float* W_in  = (const float*)d_in[3];
    const float* b_in  = (const float*)d_in[4];
    const float* W_h   = (const float*)d_in[5];
    const float* b_h   = (const float*)d_in[6];
    const float* W_out = (const float*)d_in[7];
    const float* b_out = (const float*)d_in[8];
    float* out = (float*)d_out;

    const int T = in_sizes[0];
    const int nChunks = (T + CHUNK - 1) / CHUNK;
    const int nWaves  = (nChunks + CPW - 1) / CPW;
    const size_t need = (size_t)T * sizeof(float4);

    if (ws_size >= need) {
        float4* ws4 = (float4*)d_ws;
        precompute_kernel<<<(T + 255) / 256, 256, 0, stream>>>(v_in, vs_r, fs, ws4, T);
        scan_kernel<false><<<nWaves, 64, 0, stream>>>(
            v_in, vs_r, fs, W_in, b_in, W_h, b_h, W_out, b_out, ws4, out, T);
    } else {
        scan_kernel<true><<<nWaves, 64, 0, stream>>>(
            v_in, vs_r, fs, W_in, b_in, W_h, b_h, W_out, b_out, nullptr, out, T);
    }
}

// Round 7
// 166.413 us; speedup vs baseline: 4.4343x; 1.4613x over previous
//
#include <hip/hip_runtime.h>
#include <hip/hip_bf16.h>

#define C1_CONST 4.7e-9f
#define CHUNK 15      // output steps per chunk
#define WARM  96      // warm-up steps (b1 fading-memory; validated 768/384/192 -> floor)
#define CPW   32      // chunks per wave (MFMA batch)

typedef _Float16 f16;
typedef unsigned int u32;
typedef f16   f16x8  __attribute__((ext_vector_type(8)));
typedef u32   u32x4  __attribute__((ext_vector_type(4)));
typedef float f32x16 __attribute__((ext_vector_type(16)));

#define MFMA(A, B, C) __builtin_amdgcn_mfma_f32_32x32x16_f16((A), (B), (C), 0, 0, 0)

// Dekker split of a pair: x = hi + lo/1024 (hi,lo f16, packed as u32).
// Scaling by 1024 keeps lo in f16-normal range (residual ~2^-11*x would
// otherwise be denormal and risk flushing in the matrix pipe).
__device__ __forceinline__ void splitp(float x0, float x1, u32& uh, u32& ul) {
    auto hv = __builtin_amdgcn_cvt_pkrtz(x0, x1);
    float h0 = (float)hv[0], h1 = (float)hv[1];
    auto lv = __builtin_amdgcn_cvt_pkrtz((x0 - h0) * 1024.0f, (x1 - h1) * 1024.0f);
    uh = __builtin_bit_cast(u32, hv);
    ul = __builtin_bit_cast(u32, lv);
}

// Kernel 1: parallel precompute of per-step scalars {P1, P2*v, dp_r, 0}.
// Uses the P0 == 1 identity (g0 = g1+g2 exactly).
__global__ void precompute_kernel(const float* __restrict__ v_in,
                                  const float* __restrict__ vs_r,
                                  const float* __restrict__ fs,
                                  float4* __restrict__ ws4, int T) {
    int t = blockIdx.x * blockDim.x + threadIdx.x;
    if (t >= T) return;
    float f   = fs[t];
    float vr  = vs_r[t];
    float c1r = 1.0f / (2.0f * C1_CONST * f);
    float r0  = c1r * vr / (c1r + vr);
    float g1  = 1.0f / c1r;
    float g2  = 1.0f / vr;
    float S   = 2.0f * (g1 + g2);   // g0 = g1+g2
    float P1  = 2.0f * g1 / S;
    float P2  = 2.0f * g2 / S;
    ws4[t] = make_float4(P1, P2 * v_in[t], r0 / 3000.0f, 0.0f);
}

// Kernel 2: 32 chunks per wave, hidden layers via v_mfma_f32_32x32x16_f16.
// chunk = MFMA column n = lane&31; half h = lane>>5.
//
// LOGICAL-K REMAP (exact): MFMA is invariant under any common permutation of
// A/B k-slots. We choose slot (s = which MFMA, h, jj = vector elem) ->
//   k = (jj&3) + 4*h + 8*(jj>>2) + 16*s
// so that half h's B k-set equals exactly the C/D rows it owns
// (row = (reg&3)+8*(reg>>2)+4*h). Consequence: D reg r = jj + 8*s, i.e.
//   B0 slots = relu(D[0..7]), B1 slots = relu(D[8..15])
// with ZERO cross-lane exchange between layers. A fragments and input-layer
// constants use the same permuted k at setup (free).
template <bool INLINE_PRE>
__global__ __launch_bounds__(64, 1) void scan_kernel(
    const float* __restrict__ v_in, const float* __restrict__ vs_r,
    const float* __restrict__ fs,
    const float* __restrict__ W_in, const float* __restrict__ b_in,
    const float* __restrict__ W_h,  const float* __restrict__ b_h,
    const float* __restrict__ W_out, const float* __restrict__ b_out,
    const float4* __restrict__ ws4, float* __restrict__ out, int T) {
    const int lane = threadIdx.x & 63;
    const int c    = lane & 31;   // chunk slot / MFMA col / weight row m
    const int h    = lane >> 5;
    const int xaddr = (lane ^ 32) << 2;   // ds_bpermute addr for xor-32

    auto xr32 = [&](float v) {
        return __int_as_float(__builtin_amdgcn_ds_bpermute(xaddr, __float_as_int(v)));
    };

    // ---- MFMA A fragments for the two hidden layers (hi + lo*1024) ----
    f16x8 AhA0, AlA0, AhA1, AlA1, AhB0, AlB0, AhB1, AlB1;
#pragma unroll
    for (int jj = 0; jj < 8; ++jj) {
        int k0 = (jj & 3) + 4 * h + 8 * (jj >> 2);   // s=0
        int k1 = k0 + 16;                            // s=1
        float wa0 = W_h[c * 32 + k0], wa1 = W_h[c * 32 + k1];
        float wb0 = W_h[1024 + c * 32 + k0], wb1 = W_h[1024 + c * 32 + k1];
        f16 t;
        t = (f16)wa0; AhA0[jj] = t; AlA0[jj] = (f16)((wa0 - (float)t) * 1024.0f);
        t = (f16)wa1; AhA1[jj] = t; AlA1[jj] = (f16)((wa1 - (float)t) * 1024.0f);
        t = (f16)wb0; AhB0[jj] = t; AlB0[jj] = (f16)((wb0 - (float)t) * 1024.0f);
        t = (f16)wb1; AhB1[jj] = t; AlB1[jj] = (f16)((wb1 - (float)t) * 1024.0f);
    }

    // ---- biases in C/D layout; W_out by C/D row; zero C frag ----
    f32x16 bAf, bBf, zf;
    float wo_r[16];
#pragma unroll
    for (int r = 0; r < 16; ++r) {
        int row = (r & 3) + 8 * (r >> 2) + 4 * h;
        bAf[r] = b_h[row];
        bBf[r] = b_h[32 + row];
        wo_r[r] = W_out[row];
        zf[r] = 0.0f;
    }
    const float bo = b_out[0];

    // ---- input-layer constants, in B-slot order u = s*8 + jj ----
    float wi0c[16], wi1c[16], bic[16];
#pragma unroll
    for (int s = 0; s < 2; ++s)
#pragma unroll
        for (int jj = 0; jj < 8; ++jj) {
            int k = (jj & 3) + 4 * h + 8 * (jj >> 2) + 16 * s;
            wi0c[s * 8 + jj] = W_in[2 * k];
            wi1c[s * 8 + jj] = W_in[2 * k + 1];
            bic[s * 8 + jj]  = b_in[k];
        }

    const int cg = blockIdx.x * CPW + c;   // global chunk id
    const int ts = cg * CHUNK;             // first output step of this chunk

    auto load_pre = [&](int tt, float& P1, float& pv, float& dr) {
        int tc = min(max(tt, 0), T - 1);
        if constexpr (INLINE_PRE) {
            float f   = fs[tc];
            float vr  = vs_r[tc];
            float c1r = 1.0f / (2.0f * C1_CONST * f);
            float r0  = c1r * vr / (c1r + vr);
            float g1  = 1.0f / c1r;
            float g2  = 1.0f / vr;
            float S   = 2.0f * (g1 + g2);
            P1 = 2.0f * g1 / S;
            pv = (2.0f * g2 / S) * v_in[tc];
            dr = r0 / 3000.0f;
        } else {
            float4 d = ws4[tc];
            P1 = d.x; pv = d.y; dr = d.z;
        }
    };

    float b1 = 0.0f;
    float P1, pv, dr;
    load_pre(ts - WARM, P1, pv, dr);

    for (int j = -WARM; j < CHUNK; ++j) {
        const int t = ts + j;
        // prefetch next step's scalars (independent of this step's compute)
        float nP1, npv, ndr;
        load_pre(t + 1, nP1, npv, ndr);

        // dp_a = P1*b1 + P2*v   (P0 == 1 -> a0 term vanishes)
        const float dp_a = fmaf(P1, b1, pv);

        // ---- input layer 2->32, directly in B-slot order ----
        float hv[16];
#pragma unroll
        for (int u = 0; u < 16; ++u)
            hv[u] = fmaxf(fmaf(wi0c[u], dp_a, fmaf(wi1c[u], dr, bic[u])), 0.0f);

        u32 ph0, ph1, ph2, ph3, pl0, pl1, pl2, pl3;
        splitp(hv[0], hv[1], ph0, pl0);
        splitp(hv[2], hv[3], ph1, pl1);
        splitp(hv[4], hv[5], ph2, pl2);
        splitp(hv[6], hv[7], ph3, pl3);
        f16x8 B0h = __builtin_bit_cast(f16x8, (u32x4){ph0, ph1, ph2, ph3});
        f16x8 B0l = __builtin_bit_cast(f16x8, (u32x4){pl0, pl1, pl2, pl3});
        splitp(hv[8],  hv[9],  ph0, pl0);
        splitp(hv[10], hv[11], ph1, pl1);
        splitp(hv[12], hv[13], ph2, pl2);
        splitp(hv[14], hv[15], ph3, pl3);
        f16x8 B1h = __builtin_bit_cast(f16x8, (u32x4){ph0, ph1, ph2, ph3});
        f16x8 B1l = __builtin_bit_cast(f16x8, (u32x4){pl0, pl1, pl2, pl3});

        // ---- hidden layer A ----
        f32x16 acc = MFMA(AhA0, B0h, bAf);
        acc = MFMA(AhA1, B1h, acc);
        f32x16 acc2 = MFMA(AhA0, B0l, zf);
        acc2 = MFMA(AlA0, B0h, acc2);
        acc2 = MFMA(AhA1, B1l, acc2);
        acc2 = MFMA(AlA1, B1h, acc2);

        // relu(D) IS the next B (k-remap): B0 <- regs 0..7, B1 <- regs 8..15
        float v[16];
#pragma unroll
        for (int r = 0; r < 16; ++r)
            v[r] = fmaxf(fmaf(acc2[r], 1.0f / 1024.0f, acc[r]), 0.0f);

        splitp(v[0], v[1], ph0, pl0);
        splitp(v[2], v[3], ph1, pl1);
        splitp(v[4], v[5], ph2, pl2);
        splitp(v[6], v[7], ph3, pl3);
        B0h = __builtin_bit_cast(f16x8, (u32x4){ph0, ph1, ph2, ph3});
        B0l = __builtin_bit_cast(f16x8, (u32x4){pl0, pl1, pl2, pl3});
        splitp(v[8],  v[9],  ph0, pl0);
        splitp(v[10], v[11], ph1, pl1);
        splitp(v[12], v[13], ph2, pl2);
        splitp(v[14], v[15], ph3, pl3);
        B1h = __builtin_bit_cast(f16x8, (u32x4){ph0, ph1, ph2, ph3});
        B1l = __builtin_bit_cast(f16x8, (u32x4){pl0, pl1, pl2, pl3});

        // ---- hidden layer B ----
        acc = MFMA(AhB0, B0h, bBf);
        acc = MFMA(AhB1, B1h, acc);
        acc2 = MFMA(AhB0, B0l, zf);
        acc2 = MFMA(AlB0, B0h, acc2);
        acc2 = MFMA(AhB1, B1l, acc2);
        acc2 = MFMA(AlB1, B1h, acc2);

        // ---- output layer 32->1: per-lane partial dot over C/D rows ----
        float p0 = 0.f, p1 = 0.f, p2 = 0.f, p3 = 0.f;
#pragma unroll
        for (int r = 0; r < 16; r += 4) {
            p0 = fmaf(wo_r[r],     fmaxf(fmaf(acc2[r],     1.0f / 1024.0f, acc[r]),     0.0f), p0);
            p1 = fmaf(wo_r[r + 1], fmaxf(fmaf(acc2[r + 1], 1.0f / 1024.0f, acc[r + 1]), 0.0f), p1);
            p2 = fmaf(wo_r[r + 2], fmaxf(fmaf(acc2[r + 2], 1.0f / 1024.0f, acc[r + 2]), 0.0f), p2);
            p3 = fmaf(wo_r[r + 3], fmaxf(fmaf(acc2[r + 3], 1.0f / 1024.0f, acc[r + 3]), 0.0f), p3);
        }
        float pd = (p0 + p1) + (p2 + p3);
        const float dp_b = pd + xr32(pd) + bo;   // symmetric: halves stay bit-identical

        const float sum = dp_a + dp_b;
        if (j >= 0) {                 // wave-uniform branch
            if (lane < 32 && t < T) out[t] = 0.5f * sum;
        }
        b1 = sum - b1;                // b1' = dp_b + (P1-1)*b1 + P2*v
        if (t < 0) b1 = 0.0f;         // warm-up clamp: exact b1=0 entering t=0

        P1 = nP1; pv = npv; dr = ndr;
    }
}

extern "C" void kernel_launch(void* const* d_in, const int* in_sizes, int n_in,
                              void* d_out, int out_size, void* d_ws, size_t ws_size,
                              hipStream_t stream) {
    const float* v_in  = (const float*)d_in[0];
    const float* vs_r  = (const float*)d_in[1];
    const float* fs    = (const float*)d_in[2];
    const float* W_in  = (const float*)d_in[3];
    const float* b_in  = (const float*)d_in[4];
    const float* W_h   = (const float*)d_in[5];
    const float* b_h   = (const float*)d_in[6];
    const float* W_out = (const float*)d_in[7];
    const float* b_out = (const float*)d_in[8];
    float* out = (float*)d_out;

    const int T = in_sizes[0];
    const int nChunks = (T + CHUNK - 1) / CHUNK;
    const int nWaves  = (nChunks + CPW - 1) / CPW;
    const size_t need = (size_t)T * sizeof(float4);

    if (ws_size >= need) {
        float4* ws4 = (float4*)d_ws;
        precompute_kernel<<<(T + 255) / 256, 256, 0, stream>>>(v_in, vs_r, fs, ws4, T);
        scan_kernel<false><<<nWaves, 64, 0, stream>>>(
            v_in, vs_r, fs, W_in, b_in, W_h, b_h, W_out, b_out, ws4, out, T);
    } else {
        scan_kernel<true><<<nWaves, 64, 0, stream>>>(
            v_in, vs_r, fs, W_in, b_in, W_h, b_h, W_out, b_out, nullptr, out, T);
    }
}